// Round 1
// baseline (405.698 us; speedup 1.0000x reference)
//
#include <hip/hip_runtime.h>
#include <stdint.h>

#define NB 32
#define CC 64
#define HH 112
#define WW 112
#define HW (HH * WW)          // 12544
#define NHW (NB * HW)         // 401408
#define PIX_BLOCKS (NHW / 256) // 1568, exact

// ---------------- kernel 1: binarize weights -> bits + scale; zero stat accumulators
__global__ void wpack_kernel(const float* __restrict__ wflat,
                             uint64_t* __restrict__ wbits,
                             float* __restrict__ wscale,
                             int* __restrict__ ch_sum,
                             unsigned long long* __restrict__ ch_sumsq) {
    int o = blockIdx.x;      // 64 blocks, one per output channel
    int i = threadIdx.x;     // 64 threads = input channel (lane id)
    const float* wp = wflat + (size_t)(o * 64 + i) * 9;
    float w[9];
    float asum = 0.f;
#pragma unroll
    for (int t = 0; t < 9; t++) { w[t] = wp[t]; asum += fabsf(w[t]); }
    // wave (64-lane) reduce |w| sum
#pragma unroll
    for (int s = 32; s > 0; s >>= 1) asum += __shfl_xor(asum, s, 64);
    float scale = asum * (1.0f / 576.0f);
    uint64_t b[9];
#pragma unroll
    for (int t = 0; t < 9; t++) b[t] = __ballot(w[t] >= 0.0f);  // bit i = sign(+) of channel i
    if (i == 0) {
#pragma unroll
        for (int t = 0; t < 9; t++) wbits[o * 9 + t] = b[t];
        wscale[o] = scale;
        ch_sum[o] = 0;
        ch_sumsq[o] = 0ull;
    }
}

// ---------------- kernel 2: pack sign(x) bits per pixel over 64 channels
__global__ __launch_bounds__(256) void xpack_kernel(const float* __restrict__ x,
                                                    uint64_t* __restrict__ bits) {
    int p = blockIdx.x * 256 + threadIdx.x;   // p < NHW exactly
    int n = p / HW;
    int r = p - n * HW;
    const float* xp = x + (size_t)n * CC * HW + r;
    uint64_t b = 0;
#pragma unroll
    for (int c = 0; c < 64; c++) {
        float v = xp[(size_t)c * HW];
        b |= (uint64_t)(v > 0.0f) << c;
    }
    bits[p] = b;
}

// conv core: load 9 neighbor bit-words (guarded), wave-uniform fast/masked flag
__device__ __forceinline__ void load_neighbors(const uint64_t* __restrict__ bp,
                                               int h, int w, int r,
                                               uint64_t nb[9], int vm[9], bool& fast) {
    bool inter = (h > 0) & (h < HH - 1) & (w > 0) & (w < WW - 1);
    uint64_t bal = __ballot(inter);
    fast = (bal == ~0ull);
    if (fast) {
#pragma unroll
        for (int t = 0; t < 9; t++) {
            int dh = t / 3 - 1, dw = t % 3 - 1;
            nb[t] = bp[r + dh * WW + dw];
            vm[t] = -1;
        }
    } else {
#pragma unroll
        for (int t = 0; t < 9; t++) {
            int dh = t / 3 - 1, dw = t % 3 - 1;
            int hh = h + dh, ww2 = w + dw;
            bool v = (hh >= 0) & (hh < HH) & (ww2 >= 0) & (ww2 < WW);
            vm[t] = v ? -1 : 0;
            nb[t] = v ? bp[hh * WW + ww2] : 0ull;
        }
    }
}

__device__ __forceinline__ int conv_one(const uint64_t nb[9], const int vm[9],
                                        const uint64_t* __restrict__ wrow, bool fast) {
    if (fast) {
        int pc = 0;
#pragma unroll
        for (int t = 0; t < 9; t++) pc += __popcll(nb[t] ^ wrow[t]);
        return 576 - 2 * pc;
    } else {
        int S = 0;
#pragma unroll
        for (int t = 0; t < 9; t++)
            S += vm[t] & (64 - 2 * (int)__popcll(nb[t] ^ wrow[t]));
        return S;
    }
}

// ---------------- kernel 3: conv + per-channel sum / sumsq (integer exact)
__global__ __launch_bounds__(256) void stats_kernel(const uint64_t* __restrict__ bits,
                                                    const uint64_t* __restrict__ wbits,
                                                    int* __restrict__ ch_sum,
                                                    unsigned long long* __restrict__ ch_sumsq) {
    __shared__ int ls_sum[64];
    __shared__ int ls_sq[64];
    int tid = threadIdx.x;
    if (tid < 64) { ls_sum[tid] = 0; ls_sq[tid] = 0; }
    __syncthreads();

    for (int p = blockIdx.x * 256 + tid; p < NHW; p += gridDim.x * 256) {
        int n = p / HW;
        int r = p - n * HW;
        int h = r / WW;
        int w = r - h * WW;
        const uint64_t* bp = bits + (size_t)n * HW;
        uint64_t nb[9]; int vm[9]; bool fast;
        load_neighbors(bp, h, w, r, nb, vm, fast);

        for (int o = 0; o < 64; o++) {
            int S = conv_one(nb, vm, wbits + o * 9, fast);
            int s1 = S, s2 = S * S;
#pragma unroll
            for (int d = 32; d > 0; d >>= 1) {
                s1 += __shfl_xor(s1, d, 64);
                s2 += __shfl_xor(s2, d, 64);
            }
            if ((tid & 63) == 0) {
                atomicAdd(&ls_sum[o], s1);
                atomicAdd(&ls_sq[o], s2);
            }
        }
    }
    __syncthreads();
    if (tid < 64) {
        atomicAdd(&ch_sum[tid], ls_sum[tid]);
        atomicAdd(&ch_sumsq[tid], (unsigned long long)(long long)ls_sq[tid]);
    }
}

// ---------------- kernel 4: fold BN stats into per-channel affine a,b
__global__ void bnprep_kernel(const int* __restrict__ ch_sum,
                              const unsigned long long* __restrict__ ch_sumsq,
                              const float* __restrict__ wscale,
                              const float* __restrict__ gamma,
                              const float* __restrict__ beta,
                              float* __restrict__ aC, float* __restrict__ bC) {
    int o = threadIdx.x;  // 64 threads
    double P = (double)NHW;
    double meanS = (double)ch_sum[o] / P;
    double e2 = (double)ch_sumsq[o] / P;
    double varS = e2 - meanS * meanS;
    double sc = (double)wscale[o];
    double mean_y = sc * meanS;
    double var_y = sc * sc * varS;
    double inv = (double)gamma[o] / sqrt(var_y + 1e-5);
    aC[o] = (float)(sc * inv);
    bC[o] = (float)((double)beta[o] - mean_y * inv);
}

// ---------------- kernel 5: conv again + BN affine + residual
__global__ __launch_bounds__(256) void final_kernel(const uint64_t* __restrict__ bits,
                                                    const uint64_t* __restrict__ wbits,
                                                    const float* __restrict__ aC,
                                                    const float* __restrict__ bC,
                                                    const float* __restrict__ x,
                                                    float* __restrict__ out) {
    int p = blockIdx.x * 256 + threadIdx.x;  // exact
    int n = p / HW;
    int r = p - n * HW;
    int h = r / WW;
    int w = r - h * WW;
    const uint64_t* bp = bits + (size_t)n * HW;
    uint64_t nb[9]; int vm[9]; bool fast;
    load_neighbors(bp, h, w, r, nb, vm, fast);

    const float* xp = x + (size_t)n * CC * HW + r;
    float* op = out + (size_t)n * CC * HW + r;
    for (int o = 0; o < 64; o++) {
        int S = conv_one(nb, vm, wbits + o * 9, fast);
        op[(size_t)o * HW] = (float)S * aC[o] + bC[o] + xp[(size_t)o * HW];
    }
}

extern "C" void kernel_launch(void* const* d_in, const int* in_sizes, int n_in,
                              void* d_out, int out_size, void* d_ws, size_t ws_size,
                              hipStream_t stream) {
    const float* x     = (const float*)d_in[0];
    const float* wflat = (const float*)d_in[1];
    const float* gamma = (const float*)d_in[2];
    const float* beta  = (const float*)d_in[3];
    float* out = (float*)d_out;

    char* ws = (char*)d_ws;
    // ws layout (all 8B-aligned): bits | wbits | wscale | ch_sum | ch_sumsq | aC | bC
    uint64_t* bits  = (uint64_t*)ws;                          // 401408*8 = 3,211,264 B
    uint64_t* wbits = (uint64_t*)(ws + 3211264);              // 576*8 = 4608 B
    float* wscale   = (float*)(ws + 3215872);                 // 256 B
    int* ch_sum     = (int*)(ws + 3216128);                   // 256 B
    unsigned long long* ch_sumsq = (unsigned long long*)(ws + 3216384); // 512 B
    float* aC       = (float*)(ws + 3216896);                 // 256 B
    float* bC       = (float*)(ws + 3217152);                 // 256 B

    wpack_kernel<<<64, 64, 0, stream>>>(wflat, wbits, wscale, ch_sum, ch_sumsq);
    xpack_kernel<<<PIX_BLOCKS, 256, 0, stream>>>(x, bits);
    stats_kernel<<<512, 256, 0, stream>>>(bits, wbits, ch_sum, ch_sumsq);
    bnprep_kernel<<<1, 64, 0, stream>>>(ch_sum, ch_sumsq, wscale, gamma, beta, aC, bC);
    final_kernel<<<PIX_BLOCKS, 256, 0, stream>>>(bits, wbits, aC, bC, x, out);
}

// Round 2
// 314.989 us; speedup vs baseline: 1.2880x; 1.2880x over previous
//
#include <hip/hip_runtime.h>
#include <stdint.h>

#define NB 32
#define CC 64
#define HH 112
#define WW 112
#define HW (HH * WW)            // 12544
#define NHW (NB * HW)           // 401408
#define PIX_BLOCKS (NHW / 256)  // 1568, exact
#define ROW_BLOCKS (NB * HH / 4) // 896 blocks, 4 row-waves each

// ---------------- kernel 1: binarize weights -> bits + scale; zero stat accumulators
__global__ void wpack_kernel(const float* __restrict__ wflat,
                             uint64_t* __restrict__ wbits,
                             float* __restrict__ wscale,
                             int* __restrict__ ch_sum,
                             unsigned long long* __restrict__ ch_sumsq) {
    int o = blockIdx.x;      // 64 blocks, one per output channel
    int i = threadIdx.x;     // 64 threads = input channel (lane id)
    const float* wp = wflat + (size_t)(o * 64 + i) * 9;
    float w[9];
    float asum = 0.f;
#pragma unroll
    for (int t = 0; t < 9; t++) { w[t] = wp[t]; asum += fabsf(w[t]); }
#pragma unroll
    for (int s = 32; s > 0; s >>= 1) asum += __shfl_xor(asum, s, 64);
    float scale = asum * (1.0f / 576.0f);
    uint64_t b[9];
#pragma unroll
    for (int t = 0; t < 9; t++) b[t] = __ballot(w[t] >= 0.0f);  // bit i = sign(+) of in-channel i
    if (i == 0) {
#pragma unroll
        for (int t = 0; t < 9; t++) wbits[o * 9 + t] = b[t];
        wscale[o] = scale;
        ch_sum[o] = 0;
        ch_sumsq[o] = 0ull;
    }
}

// ---------------- kernel 2: pack sign(x) bits per pixel over 64 channels
__global__ __launch_bounds__(256) void xpack_kernel(const float* __restrict__ x,
                                                    uint64_t* __restrict__ bits) {
    int p = blockIdx.x * 256 + threadIdx.x;   // p < NHW exactly
    int n = p / HW;
    int r = p - n * HW;
    const float* xp = x + (size_t)n * CC * HW + r;
    uint64_t b = 0;
#pragma unroll
    for (int c = 0; c < 64; c++) {
        float v = xp[(size_t)c * HW];
        b |= (uint64_t)(v > 0.0f) << c;
    }
    bits[p] = b;
}

// ---- shared helpers for the row-wave (lane=channel) conv structure ----

// stage 3 zero-padded bit rows (114 cols) for this wave's row into LDS
__device__ __forceinline__ void stage_rows(uint64_t (*rb)[114], const uint64_t* __restrict__ bp,
                                           int h, int lane) {
    for (int e = lane; e < 3 * 114; e += 64) {
        int t = e / 114, c = e - t * 114;
        int hh = h - 1 + t;
        uint64_t v = 0;
        if (c >= 1 && c <= 112 && hh >= 0 && hh < HH) v = bp[hh * WW + (c - 1)];
        rb[t][c] = v;
    }
}

// per-lane weight regs + boundary corrections
struct WRegs {
    uint64_t w[9];
    int corrMid, dL, dR;
};

__device__ __forceinline__ void load_wregs(WRegs& W, const uint64_t* __restrict__ wbits,
                                           int lane, int h) {
    int tc[9];
#pragma unroll
    for (int t = 0; t < 9; t++) {
        W.w[t] = wbits[lane * 9 + t];
        tc[t] = 64 - 2 * (int)__builtin_popcountll(W.w[t]);
    }
    W.corrMid = 0;
    int oL = 0, oR = 0;
    if (h == 0)      { W.corrMid = tc[0] + tc[1] + tc[2]; oL = tc[0]; oR = tc[2]; }
    if (h == HH - 1) { W.corrMid = tc[6] + tc[7] + tc[8]; oL = tc[6]; oR = tc[8]; }
    W.dL = tc[0] + tc[3] + tc[6] - oL;
    W.dR = tc[2] + tc[5] + tc[8] - oR;
}

// compute S for pixel with window cols (l,m,r), each col = 3 rows of u64
__device__ __forceinline__ int conv_px(const uint64_t l[3], const uint64_t m[3],
                                       const uint64_t r[3], const WRegs& W) {
    int pc = 0;
#pragma unroll
    for (int rr = 0; rr < 3; rr++) {
        pc += (int)__builtin_popcountll(l[rr] ^ W.w[rr * 3 + 0]);
        pc += (int)__builtin_popcountll(m[rr] ^ W.w[rr * 3 + 1]);
        pc += (int)__builtin_popcountll(r[rr] ^ W.w[rr * 3 + 2]);
    }
    return 576 - 2 * pc - W.corrMid;
}

// ---------------- kernel 3: conv + per-channel sum / sumsq (integer exact)
// wave = one image row, lane = output channel
__global__ __launch_bounds__(256) void stats2_kernel(const uint64_t* __restrict__ bits,
                                                     const uint64_t* __restrict__ wbits,
                                                     int* __restrict__ ch_sum,
                                                     unsigned long long* __restrict__ ch_sumsq) {
    __shared__ uint64_t rowbuf[4][3][114];
    __shared__ int redS[4][64];
    __shared__ int redQ[4][64];
    int tid = threadIdx.x;
    int wave = tid >> 6, lane = tid & 63;
    int rowIdx = blockIdx.x * 4 + wave;          // < 3584 exact
    int n = rowIdx / HH, h = rowIdx - n * HH;
    const uint64_t* bp = bits + (size_t)n * HW;

    stage_rows(rowbuf[wave], bp, h, lane);
    WRegs W;
    load_wregs(W, wbits, lane, h);
    __syncthreads();

    const uint64_t(*rb)[114] = rowbuf[wave];
    int s1 = 0, s2 = 0;
    uint64_t win[3][3];
    for (int c0 = 0; c0 < WW; c0 += 16) {
#pragma unroll
        for (int rr = 0; rr < 3; rr++) { win[0][rr] = rb[rr][c0]; win[1][rr] = rb[rr][c0 + 1]; }
#pragma unroll
        for (int j = 0; j < 16; j++) {
#pragma unroll
            for (int rr = 0; rr < 3; rr++) win[(j + 2) % 3][rr] = rb[rr][c0 + j + 2];
            int S = conv_px(win[j % 3], win[(j + 1) % 3], win[(j + 2) % 3], W);
            int w = c0 + j;
            if (w == 0) S -= W.dL;
            if (w == WW - 1) S -= W.dR;
            s1 += S;
            s2 += S * S;
        }
    }
    redS[wave][lane] = s1;
    redQ[wave][lane] = s2;
    __syncthreads();
    if (tid < 64) {
        int t1 = redS[0][tid] + redS[1][tid] + redS[2][tid] + redS[3][tid];
        int t2 = redQ[0][tid] + redQ[1][tid] + redQ[2][tid] + redQ[3][tid];
        atomicAdd(&ch_sum[tid], t1);
        atomicAdd(&ch_sumsq[tid], (unsigned long long)(long long)t2);
    }
}

// ---------------- kernel 4: fold BN stats into per-channel affine a,b
__global__ void bnprep_kernel(const int* __restrict__ ch_sum,
                              const unsigned long long* __restrict__ ch_sumsq,
                              const float* __restrict__ wscale,
                              const float* __restrict__ gamma,
                              const float* __restrict__ beta,
                              float* __restrict__ aC, float* __restrict__ bC) {
    int o = threadIdx.x;  // 64 threads
    double P = (double)NHW;
    double meanS = (double)ch_sum[o] / P;
    double e2 = (double)ch_sumsq[o] / P;
    double varS = e2 - meanS * meanS;
    double sc = (double)wscale[o];
    double mean_y = sc * meanS;
    double var_y = sc * sc * varS;
    double inv = (double)gamma[o] / sqrt(var_y + 1e-5);
    aC[o] = (float)(sc * inv);
    bC[o] = (float)((double)beta[o] - mean_y * inv);
}

// ---------------- kernel 5: conv again + BN affine + residual, coalesced via LDS transpose
__global__ __launch_bounds__(256) void final2_kernel(const uint64_t* __restrict__ bits,
                                                     const uint64_t* __restrict__ wbits,
                                                     const float* __restrict__ aC,
                                                     const float* __restrict__ bC,
                                                     const float* __restrict__ x,
                                                     float* __restrict__ out) {
    __shared__ uint64_t rowbuf[4][3][114];
    __shared__ float tile[4][64][17];   // [wave][channel][pixel-in-chunk], padded
    int tid = threadIdx.x;
    int wave = tid >> 6, lane = tid & 63;
    int rowIdx = blockIdx.x * 4 + wave;
    int n = rowIdx / HH, h = rowIdx - n * HH;
    const uint64_t* bp = bits + (size_t)n * HW;

    stage_rows(rowbuf[wave], bp, h, lane);
    WRegs W;
    load_wregs(W, wbits, lane, h);
    float a = aC[lane], b = bC[lane];
    __syncthreads();

    const uint64_t(*rb)[114] = rowbuf[wave];
    int cg = lane >> 4, wi = lane & 15;
    size_t rowbase = (size_t)n * CC * HW + (size_t)h * WW;
    uint64_t win[3][3];
    for (int c0 = 0; c0 < WW; c0 += 16) {
#pragma unroll
        for (int rr = 0; rr < 3; rr++) { win[0][rr] = rb[rr][c0]; win[1][rr] = rb[rr][c0 + 1]; }
#pragma unroll
        for (int j = 0; j < 16; j++) {
#pragma unroll
            for (int rr = 0; rr < 3; rr++) win[(j + 2) % 3][rr] = rb[rr][c0 + j + 2];
            int S = conv_px(win[j % 3], win[(j + 1) % 3], win[(j + 2) % 3], W);
            int w = c0 + j;
            if (w == 0) S -= W.dL;
            if (w == WW - 1) S -= W.dR;
            tile[wave][lane][j] = (float)S * a + b;
        }
        __syncthreads();
        // transposed write-out: lane = (cg, wi); 4 channel-groups x 16 consecutive w
#pragma unroll
        for (int k = 0; k < 16; k++) {
            int ch = k * 4 + cg;
            float y = tile[wave][ch][wi];
            size_t off = rowbase + (size_t)ch * HW + c0 + wi;
            out[off] = y + x[off];
        }
        __syncthreads();
    }
}

extern "C" void kernel_launch(void* const* d_in, const int* in_sizes, int n_in,
                              void* d_out, int out_size, void* d_ws, size_t ws_size,
                              hipStream_t stream) {
    const float* x     = (const float*)d_in[0];
    const float* wflat = (const float*)d_in[1];
    const float* gamma = (const float*)d_in[2];
    const float* beta  = (const float*)d_in[3];
    float* out = (float*)d_out;

    char* ws = (char*)d_ws;
    uint64_t* bits  = (uint64_t*)ws;                          // 401408*8 = 3,211,264 B
    uint64_t* wbits = (uint64_t*)(ws + 3211264);              // 576*8 = 4608 B
    float* wscale   = (float*)(ws + 3215872);                 // 256 B
    int* ch_sum     = (int*)(ws + 3216128);                   // 256 B
    unsigned long long* ch_sumsq = (unsigned long long*)(ws + 3216384); // 512 B
    float* aC       = (float*)(ws + 3216896);                 // 256 B
    float* bC       = (float*)(ws + 3217152);                 // 256 B

    wpack_kernel<<<64, 64, 0, stream>>>(wflat, wbits, wscale, ch_sum, ch_sumsq);
    xpack_kernel<<<PIX_BLOCKS, 256, 0, stream>>>(x, bits);
    stats2_kernel<<<ROW_BLOCKS, 256, 0, stream>>>(bits, wbits, ch_sum, ch_sumsq);
    bnprep_kernel<<<1, 64, 0, stream>>>(ch_sum, ch_sumsq, wscale, gamma, beta, aC, bC);
    final2_kernel<<<ROW_BLOCKS, 256, 0, stream>>>(bits, wbits, aC, bC, x, out);
}